// Round 5
// baseline (192.300 us; speedup 1.0000x reference)
//
#include <hip/hip_runtime.h>
#include <hip/hip_bf16.h>
#include <math.h>

// IDSCT2: out[b,u,v] = sum_{p,q} x[b,p,q] * S[u,p] * C[v,q]
// R10: parity-folded GEMMs (R8 math, verified), single-barrier K-loop
// (R9, verified), now with the intra-tile schedule UN-PINNED: no manual
// lgkmcnt(0)/sched_barrier(0) between ds_read and MFMA. Plain vector
// loads mean the compiler tracks ds_read->MFMA deps and emits fine-
// grained lgkmcnt (m97 asm evidence), so MFMA_E issues as soon as its
// frags land while O-reads + glds still stream. E/O get separate frag
// arrays to avoid anti-dep serialization. Rationale: 2 waves/SIMD
// (register-capped) leaves only intra-wave ILP to overlap the 16 KiB/
// tile/wave LDS reads with MFMA; R9's forced drains serialized them
// (LDS pipe 45% busy, matrix pipe 9% busy).
// Per tile: {16 ds_read_b128 (E+O), 6 glds (tile t+2), 32 MFMA,
// vmcnt(6), s_barrier}. Triple-buffered LDS: stage(t+2)/compute(t)
// disjoint; vmcnt(6)+barrier retires+publishes tile t+1 (ledger: 12
// outstanding -> 6). 33 barriers total.
//   C[2047-v,q] = (-1)^q C[v,q];  S[2047-u,p] = -(-1)^p S[u,p]
// pass1: Et/Ot (even/odd q), tT[v']=Et+Ot, tT[2047-v']=Et-Ot, output
// p-parity-split (tTe/tTo) to feed pass2 directly.
// pass2: E2/O2 (even/odd p), out[u']=E2+O2, out[2047-u']=O2-E2 (fp32).
// Swizzle (both-sides, rule #21): 64B rows = 4 chunks; slot =
// chunk ^ ((row>>1)&3) via pre-swizzled global src (linear glds dest);
// ds_read applies the same XOR -> conflict-free b128 (R8/R9 measured 0).

#define BM 128   // output rows per block (v' / u')
#define BN 256   // output cols per block (p / v)
#define BK 32
#define KDIM 1024

typedef __bf16 bf16x8 __attribute__((ext_vector_type(8)));
typedef __bf16 bf16x4 __attribute__((ext_vector_type(4)));
typedef float floatx4 __attribute__((ext_vector_type(4)));

__device__ __forceinline__ void async_ld16(const void* g, void* l) {
    __builtin_amdgcn_global_load_lds(
        (__attribute__((address_space(1))) void*)(g),
        (__attribute__((address_space(3))) void*)(l), 16, 0, 0);
}

#define BARX() __builtin_amdgcn_s_barrier()
#define VM6() asm volatile("s_waitcnt vmcnt(6)" ::: "memory")
#define VM0() asm volatile("s_waitcnt vmcnt(0)" ::: "memory")
#define NOPSTMT ((void)0)

// Basis + deinterleave-convert x. Integer phase mod 8192 keeps trig arg
// exact: arg = pi/4096 * phase.
//   Ce[v',j]=cos(pi(2v'+1)(2j)/4096)   Co: (2j+1)
//   Se[u',m]=sin(pi(2u'+1)(2m)/4096)   So: (2m+1)
//   xe[b,p,m]=x[b,p,2m]  xo: 2m+1
__global__ void prep_kernel(const float4* __restrict__ x,
                            bf16x4* __restrict__ xe, bf16x4* __restrict__ xo,
                            __bf16* __restrict__ Ce, __bf16* __restrict__ Co,
                            __bf16* __restrict__ Se, __bf16* __restrict__ So) {
    int b = blockIdx.x;
    if (b < 4096) {  // 1M basis entries
        int idx = b * 256 + threadIdx.x;
        int vp = idx >> 10;
        int j = idx & 1023;
        int pe = ((2 * vp + 1) * (2 * j)) & 8191;
        int po = ((2 * vp + 1) * (2 * j + 1)) & 8191;
        float ae = (float)pe * 7.669903939428206e-04f;  // pi/4096
        float ao = (float)po * 7.669903939428206e-04f;
        float se, ce, so, co;
        __sincosf(ae, &se, &ce);
        __sincosf(ao, &so, &co);
        Ce[idx] = (__bf16)ce;
        Co[idx] = (__bf16)co;
        Se[idx] = (__bf16)se;
        So[idx] = (__bf16)so;
    } else {  // 2M threads, 8 floats each
        int g = (b - 4096) * 256 + threadIdx.x;
        float4 v0 = x[2 * g];
        float4 v1 = x[2 * g + 1];
        bf16x4 e, o;
        e[0] = (__bf16)v0.x; e[1] = (__bf16)v0.z;
        e[2] = (__bf16)v1.x; e[3] = (__bf16)v1.z;
        o[0] = (__bf16)v0.y; o[1] = (__bf16)v0.w;
        o[2] = (__bf16)v1.y; o[3] = (__bf16)v1.w;
        xe[g] = e;
        xo[g] = o;
    }
}

// Parity-folded NT GEMM. A{e,o}: [1024][1024] (shared over z).
// B{e,o}: [z][2048][1024]. PASS=1: D0/D1 = tTe/tTo [z][2048][1024] bf16,
// fold rows v', 2047-v' and split output cols by parity.
// PASS=2: Df = out [z][2048][2048] fp32, fold rows u', 2047-u'.
template <int PASS>
__global__ void __launch_bounds__(512, 2) gemm_eo(
    const __bf16* __restrict__ Ae, const __bf16* __restrict__ Ao,
    const __bf16* __restrict__ Be, const __bf16* __restrict__ Bo,
    __bf16* __restrict__ D0, __bf16* __restrict__ D1,
    float* __restrict__ Df) {
    // per buffer: Ae[128*32] Ao[128*32] Be[256*32] Bo[256*32] = 24576 elems
    __shared__ __bf16 lds[3][24576];  // 144 KiB
    constexpr int OFF_AE = 0, OFF_AO = 4096, OFF_BE = 8192, OFF_BO = 16384;

    const int tid = threadIdx.x;
    const int lane = tid & 63;
    const int wave = tid >> 6;   // 0..7
    const int wr = wave >> 2;    // 0..1: row offset wr*64
    const int wc = wave & 3;     // 0..3: col offset wc*64

    const size_t zB = (size_t)blockIdx.z * 2048 * 1024;
    Be += zB; Bo += zB;

    const int row0 = blockIdx.y * BM;   // v'/u' in [0,1024)
    const int col0 = blockIdx.x * BN;   // p/v  in [0,2048)

    // ---- staging: one glds = 512 thr x 16B = 8 KiB = 128 rows of 64B.
    // lane slot within 16-row window freely assignable -> choose
    // global chunk = slot ^ ((row>>1)&3) (involution, shared with reads).
    const int srow = tid >> 2;
    const int scs = tid & 3;
    const int sgc = (scs ^ ((srow >> 1) & 3)) * 8;
    const __bf16* aeS = Ae + (size_t)(row0 + srow) * KDIM + sgc;
    const __bf16* aoS = Ao + (size_t)(row0 + srow) * KDIM + sgc;
    const __bf16* beS = Be + (size_t)(col0 + srow) * KDIM + sgc;
    const __bf16* boS = Bo + (size_t)(col0 + srow) * KDIM + sgc;
    const int ldsW = wave << 9;  // wave-uniform dest base (elems)

    auto STG_E = [&](int s, int kt) {
        async_ld16(aeS + kt * BK, &lds[s][OFF_AE + ldsW]);
        async_ld16(beS + kt * BK, &lds[s][OFF_BE + ldsW]);
        async_ld16(beS + kt * BK + (size_t)128 * KDIM,
                   &lds[s][OFF_BE + 4096 + ldsW]);
    };
    auto STG_O = [&](int s, int kt) {
        async_ld16(aoS + kt * BK, &lds[s][OFF_AO + ldsW]);
        async_ld16(boS + kt * BK, &lds[s][OFF_BO + ldsW]);
        async_ld16(boS + kt * BK + (size_t)128 * KDIM,
                   &lds[s][OFF_BO + 4096 + ldsW]);
    };

    // ---- fragment reads: m/n = lane&15 (+16*frag), k-chunk = lane>>4;
    // stored slot = chunk ^ ((fr>>1)&3) (frag row offsets are mult of 16
    // so only fr enters the swizzle) -> conflict-free b128.
    const int fr = lane & 15;
    const int fc = lane >> 4;
    const int slotOff = (fc ^ ((fr >> 1) & 3)) * 8;
    const int aBase = (wr * 64 + fr) * BK + slotOff;
    const int bBase = (wc * 64 + fr) * BK + slotOff;

    // Separate E/O fragment arrays: no anti-dependencies, compiler can
    // overlap MMA(E) with the O-reads freely.
    bf16x8 afrE[4], bfrE[4], afrO[4], bfrO[4];
    floatx4 accE[4][4] = {};
    floatx4 accO[4][4] = {};

    auto LDF = [&](const __bf16* buf, int aOff, int bOff,
                   bf16x8(&af)[4], bf16x8(&bf)[4]) {
#pragma unroll
        for (int i = 0; i < 4; ++i)
            af[i] = *(const bf16x8*)&buf[aOff + aBase + i * 16 * BK];
#pragma unroll
        for (int j = 0; j < 4; ++j)
            bf[j] = *(const bf16x8*)&buf[bOff + bBase + j * 16 * BK];
    };
    auto MMA16 = [&](floatx4(&acc)[4][4], bf16x8(&af)[4], bf16x8(&bf)[4]) {
        __builtin_amdgcn_s_setprio(1);
#pragma unroll
        for (int i = 0; i < 4; ++i)
#pragma unroll
            for (int j = 0; j < 4; ++j)
                acc[i][j] = __builtin_amdgcn_mfma_f32_16x16x32_bf16(
                    af[i], bf[j], acc[i][j], 0, 0, 0);
        __builtin_amdgcn_s_setprio(0);
    };

    // One K-tile = one barrier. All 16 ds_reads issued up front; the
    // compiler inserts fine-grained lgkmcnt so MMA(E) starts while the
    // O-reads / glds are still in flight. Triple buffer keeps stage(t+2)
    // address-disjoint from compute(t). End-of-tile vmcnt(6) retires
    // tile t+1's 6 glds; the barrier publishes them to all waves.
#define TILE(bc, SE, SO, VMW) do {                              \
        LDF(lds[bc], OFF_AE, OFF_BE, afrE, bfrE);               \
        LDF(lds[bc], OFF_AO, OFF_BO, afrO, bfrO);               \
        SE; SO;                                                 \
        MMA16(accE, afrE, bfrE);                                \
        MMA16(accO, afrO, bfrO);                                \
        VMW; BARX();                                            \
    } while (0)

    // Prologue: tiles 0,1 staged (12 glds); vmcnt(6) retires tile 0.
    STG_E(0, 0); STG_O(0, 0);
    STG_E(1, 1); STG_O(1, 1);
    VM6();
    BARX();

    // 32 K-tiles; unroll by 3 for static buffer indices (t%3).
    for (int i = 0; i < 10; ++i) {
        const int t = 3 * i;
        TILE(0, STG_E(2, t + 2), STG_O(2, t + 2), VM6());
        TILE(1, STG_E(0, t + 3), STG_O(0, t + 3), VM6());
        TILE(2, STG_E(1, t + 4), STG_O(1, t + 4), VM6());
    }
    TILE(0, NOPSTMT, NOPSTMT, VM0());   // tile 30: drain tile 31's glds
    TILE(1, NOPSTMT, NOPSTMT, NOPSTMT); // tile 31
#undef TILE

    // Epilogue. C/D layout: col=lane&15, row=(lane>>4)*4+reg (verified R1).
    const int ecol = lane & 15;
    const int erow = (lane >> 4) * 4;
#pragma unroll
    for (int i = 0; i < 4; ++i)
#pragma unroll
        for (int j = 0; j < 4; ++j)
#pragma unroll
            for (int r = 0; r < 4; ++r) {
                const int gi = row0 + wr * 64 + i * 16 + erow + r;
                const int gj = col0 + wc * 64 + j * 16 + ecol;
                const float e = accE[i][j][r];
                const float o = accO[i][j][r];
                if (PASS == 1) {
                    // tT[gi] = e+o ; tT[2047-gi] = e-o ; split col parity
                    __bf16* base = (gj & 1) ? D1 : D0;
                    base += zB;
                    const size_t m = (size_t)(gj >> 1);
                    base[(size_t)gi * 1024 + m] = (__bf16)(e + o);
                    base[(size_t)(2047 - gi) * 1024 + m] = (__bf16)(e - o);
                } else {
                    // out[gi] = e+o ; out[2047-gi] = o-e
                    float* ob = Df + (size_t)blockIdx.z * 2048 * 2048;
                    ob[(size_t)gi * 2048 + gj] = e + o;
                    ob[(size_t)(2047 - gi) * 2048 + gj] = o - e;
                }
            }
}

extern "C" void kernel_launch(void* const* d_in, const int* in_sizes, int n_in,
                              void* d_out, int out_size, void* d_ws, size_t ws_size,
                              hipStream_t stream) {
    const float* x = (const float*)d_in[0];
    float* out = (float*)d_out;

    const size_t m1 = (size_t)1024 * 1024;  // basis elems (2 MiB each)
    const size_t hm = (size_t)4 * 2048 * 1024;  // half-matrix batch: 8M elems

    // Workspace (72 MiB): Ce,Co,Se,So (8 MiB) | xe,xo (32) | tTe,tTo (32)
    __bf16* Ce = (__bf16*)d_ws;
    __bf16* Co = Ce + m1;
    __bf16* Se = Co + m1;
    __bf16* So = Se + m1;
    __bf16* xe = So + m1;
    __bf16* xo = xe + hm;
    __bf16* tTe = xo + hm;
    __bf16* tTo = tTe + hm;

    // 4096 basis blocks + 8192 deinterleave blocks
    prep_kernel<<<12288, 256, 0, stream>>>((const float4*)x, (bf16x4*)xe,
                                           (bf16x4*)xo, Ce, Co, Se, So);

    dim3 grid(2048 / BN, 1024 / BM, 4);  // (8, 8, 4) = 256 blocks
    // pass1: Et/Ot over q-parity; epilogue folds v' and splits p-parity
    gemm_eo<1><<<grid, 512, 0, stream>>>(Ce, Co, xe, xo, tTe, tTo, nullptr);
    // pass2: E2/O2 over p-parity; epilogue folds u', writes fp32 out
    gemm_eo<2><<<grid, 512, 0, stream>>>(Se, So, tTe, tTo, nullptr, nullptr, out);
}

// Round 6
// 192.058 us; speedup vs baseline: 1.0013x; 1.0013x over previous
//
#include <hip/hip_runtime.h>
#include <hip/hip_bf16.h>
#include <math.h>

// IDSCT2: out[b,u,v] = sum_{p,q} x[b,p,q] * S[u,p] * C[v,q]
// R11: parity-folded GEMMs (R8 math), triple-buffered single-barrier
// K-loop (R9 ledger), now ANTI-PHASED: waves 0-3 process E-then-O,
// waves 4-7 O-then-E. Waves w and w+4 share a SIMD (round-robin), so
// when one is in its 16-MFMA cluster its SIMD-mate is in its 8-read
// cluster -> matrix-pipe work spreads across the tile window instead of
// bunching after the read phase (R10 counters: MfmaUtil 27% = per-SIMD
// MFMA time fully serialized after reads; both pipes <50% busy).
// setprio(1) around MFMA arbitrates the role-split (T5).
// Within a wave, P2's reads are issued before MMA_P1 (DS ops retire in
// order, so MMA_P1 only waits on P1's reads) -- P2 reads can hide under
// MMA_P1 if the compiler emits fine-grained lgkmcnt.
// Per tile: {8 ds_read (P1), 3 glds, 8 ds_read (P2), 3 glds,
// 16 MFMA (P1), 16 MFMA (P2), vmcnt(6), s_barrier}. All reads consumed
// before the barrier (no in-flight LDS read crosses it). vmcnt(6)
// retires tile t+1's 6 glds; barrier publishes. 33 barriers/dispatch.
//   C[2047-v,q] = (-1)^q C[v,q];  S[2047-u,p] = -(-1)^p S[u,p]
// pass1: Et/Ot (even/odd q), tT[v']=Et+Ot, tT[2047-v']=Et-Ot, output
// p-parity-split (tTe/tTo) to feed pass2 directly.
// pass2: E2/O2 (even/odd p), out[u']=E2+O2, out[2047-u']=O2-E2 (fp32).
// Swizzle (both-sides, rule #21): 64B rows = 4 chunks; slot =
// chunk ^ ((row>>1)&3) via pre-swizzled global src (linear glds dest);
// ds_read applies the same XOR -> conflict-free b128 (R8-R10 measured 0).

#define BM 128   // output rows per block (v' / u')
#define BN 256   // output cols per block (p / v)
#define BK 32
#define KDIM 1024

typedef __bf16 bf16x8 __attribute__((ext_vector_type(8)));
typedef __bf16 bf16x4 __attribute__((ext_vector_type(4)));
typedef float floatx4 __attribute__((ext_vector_type(4)));

__device__ __forceinline__ void async_ld16(const void* g, void* l) {
    __builtin_amdgcn_global_load_lds(
        (__attribute__((address_space(1))) void*)(g),
        (__attribute__((address_space(3))) void*)(l), 16, 0, 0);
}

#define BARX() __builtin_amdgcn_s_barrier()
#define VM6() asm volatile("s_waitcnt vmcnt(6)" ::: "memory")
#define VM0() asm volatile("s_waitcnt vmcnt(0)" ::: "memory")
#define NOPSTMT ((void)0)

// Basis + deinterleave-convert x. Integer phase mod 8192 keeps trig arg
// exact: arg = pi/4096 * phase.
//   Ce[v',j]=cos(pi(2v'+1)(2j)/4096)   Co: (2j+1)
//   Se[u',m]=sin(pi(2u'+1)(2m)/4096)   So: (2m+1)
//   xe[b,p,m]=x[b,p,2m]  xo: 2m+1
__global__ void prep_kernel(const float4* __restrict__ x,
                            bf16x4* __restrict__ xe, bf16x4* __restrict__ xo,
                            __bf16* __restrict__ Ce, __bf16* __restrict__ Co,
                            __bf16* __restrict__ Se, __bf16* __restrict__ So) {
    int b = blockIdx.x;
    if (b < 4096) {  // 1M basis entries
        int idx = b * 256 + threadIdx.x;
        int vp = idx >> 10;
        int j = idx & 1023;
        int pe = ((2 * vp + 1) * (2 * j)) & 8191;
        int po = ((2 * vp + 1) * (2 * j + 1)) & 8191;
        float ae = (float)pe * 7.669903939428206e-04f;  // pi/4096
        float ao = (float)po * 7.669903939428206e-04f;
        float se, ce, so, co;
        __sincosf(ae, &se, &ce);
        __sincosf(ao, &so, &co);
        Ce[idx] = (__bf16)ce;
        Co[idx] = (__bf16)co;
        Se[idx] = (__bf16)se;
        So[idx] = (__bf16)so;
    } else {  // 2M threads, 8 floats each
        int g = (b - 4096) * 256 + threadIdx.x;
        float4 v0 = x[2 * g];
        float4 v1 = x[2 * g + 1];
        bf16x4 e, o;
        e[0] = (__bf16)v0.x; e[1] = (__bf16)v0.z;
        e[2] = (__bf16)v1.x; e[3] = (__bf16)v1.z;
        o[0] = (__bf16)v0.y; o[1] = (__bf16)v0.w;
        o[2] = (__bf16)v1.y; o[3] = (__bf16)v1.w;
        xe[g] = e;
        xo[g] = o;
    }
}

// Parity-folded NT GEMM. A{e,o}: [1024][1024] (shared over z).
// B{e,o}: [z][2048][1024]. PASS=1: D0/D1 = tTe/tTo [z][2048][1024] bf16,
// fold rows v', 2047-v' and split output cols by parity.
// PASS=2: Df = out [z][2048][2048] fp32, fold rows u', 2047-u'.
template <int PASS>
__global__ void __launch_bounds__(512, 2) gemm_eo(
    const __bf16* __restrict__ Ae, const __bf16* __restrict__ Ao,
    const __bf16* __restrict__ Be, const __bf16* __restrict__ Bo,
    __bf16* __restrict__ D0, __bf16* __restrict__ D1,
    float* __restrict__ Df) {
    // per buffer: Ae[128*32] Ao[128*32] Be[256*32] Bo[256*32] = 24576 elems
    __shared__ __bf16 lds[3][24576];  // 144 KiB
    constexpr int OFF_AE = 0, OFF_AO = 4096, OFF_BE = 8192, OFF_BO = 16384;

    const int tid = threadIdx.x;
    const int lane = tid & 63;
    const int wave = tid >> 6;   // 0..7
    const int wr = wave >> 2;    // 0..1: row offset wr*64
    const int wc = wave & 3;     // 0..3: col offset wc*64

    const size_t zB = (size_t)blockIdx.z * 2048 * 1024;
    Be += zB; Bo += zB;

    const int row0 = blockIdx.y * BM;   // v'/u' in [0,1024)
    const int col0 = blockIdx.x * BN;   // p/v  in [0,2048)

    // ---- staging: one glds = 512 thr x 16B = 8 KiB = 128 rows of 64B.
    // lane slot within 16-row window freely assignable -> choose
    // global chunk = slot ^ ((row>>1)&3) (involution, shared with reads).
    const int srow = tid >> 2;
    const int scs = tid & 3;
    const int sgc = (scs ^ ((srow >> 1) & 3)) * 8;
    const __bf16* aeS = Ae + (size_t)(row0 + srow) * KDIM + sgc;
    const __bf16* aoS = Ao + (size_t)(row0 + srow) * KDIM + sgc;
    const __bf16* beS = Be + (size_t)(col0 + srow) * KDIM + sgc;
    const __bf16* boS = Bo + (size_t)(col0 + srow) * KDIM + sgc;
    const int ldsW = wave << 9;  // wave-uniform dest base (elems)

    auto STG_E = [&](int s, int kt) {
        async_ld16(aeS + kt * BK, &lds[s][OFF_AE + ldsW]);
        async_ld16(beS + kt * BK, &lds[s][OFF_BE + ldsW]);
        async_ld16(beS + kt * BK + (size_t)128 * KDIM,
                   &lds[s][OFF_BE + 4096 + ldsW]);
    };
    auto STG_O = [&](int s, int kt) {
        async_ld16(aoS + kt * BK, &lds[s][OFF_AO + ldsW]);
        async_ld16(boS + kt * BK, &lds[s][OFF_BO + ldsW]);
        async_ld16(boS + kt * BK + (size_t)128 * KDIM,
                   &lds[s][OFF_BO + 4096 + ldsW]);
    };

    // ---- fragment reads: m/n = lane&15 (+16*frag), k-chunk = lane>>4;
    // stored slot = chunk ^ ((fr>>1)&3) (frag row offsets are mult of 16
    // so only fr enters the swizzle) -> conflict-free b128.
    const int fr = lane & 15;
    const int fc = lane >> 4;
    const int slotOff = (fc ^ ((fr >> 1) & 3)) * 8;
    const int aBase = (wr * 64 + fr) * BK + slotOff;
    const int bBase = (wc * 64 + fr) * BK + slotOff;

    // Separate E/O fragment arrays: no anti-dependencies across parities.
    bf16x8 afrE[4], bfrE[4], afrO[4], bfrO[4];
    floatx4 accE[4][4] = {};
    floatx4 accO[4][4] = {};

    auto LDF = [&](const __bf16* buf, int aOff, int bOff,
                   bf16x8(&af)[4], bf16x8(&bf)[4]) {
#pragma unroll
        for (int i = 0; i < 4; ++i)
            af[i] = *(const bf16x8*)&buf[aOff + aBase + i * 16 * BK];
#pragma unroll
        for (int j = 0; j < 4; ++j)
            bf[j] = *(const bf16x8*)&buf[bOff + bBase + j * 16 * BK];
    };
    auto MMA16 = [&](floatx4(&acc)[4][4], bf16x8(&af)[4], bf16x8(&bf)[4]) {
        __builtin_amdgcn_s_setprio(1);
#pragma unroll
        for (int i = 0; i < 4; ++i)
#pragma unroll
            for (int j = 0; j < 4; ++j)
                acc[i][j] = __builtin_amdgcn_mfma_f32_16x16x32_bf16(
                    af[i], bf[j], acc[i][j], 0, 0, 0);
        __builtin_amdgcn_s_setprio(0);
    };

    // One K-tile = one barrier. P1's reads -> P2's reads -> MMA_P1 (waits
    // only P1 reads; DS retires in order) -> MMA_P2 -> vmcnt(6) -> bar.
    // Triple buffer keeps stage(t+2) disjoint from compute(t); all LDS
    // reads are consumed (hence retired) before the barrier.
#define TILE_(bc, P1, P2, SA, SB, VMW) do {                         \
        LDF(lds[bc], OFF_A##P1, OFF_B##P1, afr##P1, bfr##P1); SA;   \
        LDF(lds[bc], OFF_A##P2, OFF_B##P2, afr##P2, bfr##P2); SB;   \
        MMA16(acc##P1, afr##P1, bfr##P1);                           \
        MMA16(acc##P2, afr##P2, bfr##P2);                           \
        VMW; BARX();                                                \
    } while (0)

    // Full schedule for parity order (P1 first): prologue stages tiles
    // 0,1 (12 glds, vmcnt(6) retires tile 0); 30 steady tiles (unroll 3
    // for static buffer indices); tail drains.
#define RUN(P1, P2) do {                                                  \
        STG_##P1(0, 0); STG_##P2(0, 0);                                   \
        STG_##P1(1, 1); STG_##P2(1, 1);                                   \
        VM6();                                                            \
        BARX();                                                           \
        for (int i = 0; i < 10; ++i) {                                    \
            const int t = 3 * i;                                          \
            TILE_(0, P1, P2, STG_##P1(2, t + 2), STG_##P2(2, t + 2), VM6()); \
            TILE_(1, P1, P2, STG_##P1(0, t + 3), STG_##P2(0, t + 3), VM6()); \
            TILE_(2, P1, P2, STG_##P1(1, t + 4), STG_##P2(1, t + 4), VM6()); \
        }                                                                 \
        TILE_(0, P1, P2, NOPSTMT, NOPSTMT, VM0());                        \
        TILE_(1, P1, P2, NOPSTMT, NOPSTMT, NOPSTMT);                      \
    } while (0)

    // Anti-phase: waves 0-3 E-first, waves 4-7 O-first. Waves w and w+4
    // land on the same SIMD (round-robin w%4), so SIMD-mates run MFMA
    // and read clusters in opposition. Both paths execute identical
    // barrier sequences (34 barriers), wave-uniform branching.
    if ((wave >> 2) == 0) {
        RUN(E, O);
    } else {
        RUN(O, E);
    }
#undef RUN
#undef TILE_

    // Epilogue. C/D layout: col=lane&15, row=(lane>>4)*4+reg (verified R1).
    const int ecol = lane & 15;
    const int erow = (lane >> 4) * 4;
#pragma unroll
    for (int i = 0; i < 4; ++i)
#pragma unroll
        for (int j = 0; j < 4; ++j)
#pragma unroll
            for (int r = 0; r < 4; ++r) {
                const int gi = row0 + wr * 64 + i * 16 + erow + r;
                const int gj = col0 + wc * 64 + j * 16 + ecol;
                const float e = accE[i][j][r];
                const float o = accO[i][j][r];
                if (PASS == 1) {
                    // tT[gi] = e+o ; tT[2047-gi] = e-o ; split col parity
                    __bf16* base = (gj & 1) ? D1 : D0;
                    base += zB;
                    const size_t m = (size_t)(gj >> 1);
                    base[(size_t)gi * 1024 + m] = (__bf16)(e + o);
                    base[(size_t)(2047 - gi) * 1024 + m] = (__bf16)(e - o);
                } else {
                    // out[gi] = e+o ; out[2047-gi] = o-e
                    float* ob = Df + (size_t)blockIdx.z * 2048 * 2048;
                    ob[(size_t)gi * 2048 + gj] = e + o;
                    ob[(size_t)(2047 - gi) * 2048 + gj] = o - e;
                }
            }
}

extern "C" void kernel_launch(void* const* d_in, const int* in_sizes, int n_in,
                              void* d_out, int out_size, void* d_ws, size_t ws_size,
                              hipStream_t stream) {
    const float* x = (const float*)d_in[0];
    float* out = (float*)d_out;

    const size_t m1 = (size_t)1024 * 1024;  // basis elems (2 MiB each)
    const size_t hm = (size_t)4 * 2048 * 1024;  // half-matrix batch: 8M elems

    // Workspace (72 MiB): Ce,Co,Se,So (8 MiB) | xe,xo (32) | tTe,tTo (32)
    __bf16* Ce = (__bf16*)d_ws;
    __bf16* Co = Ce + m1;
    __bf16* Se = Co + m1;
    __bf16* So = Se + m1;
    __bf16* xe = So + m1;
    __bf16* xo = xe + hm;
    __bf16* tTe = xo + hm;
    __bf16* tTo = tTe + hm;

    // 4096 basis blocks + 8192 deinterleave blocks
    prep_kernel<<<12288, 256, 0, stream>>>((const float4*)x, (bf16x4*)xe,
                                           (bf16x4*)xo, Ce, Co, Se, So);

    dim3 grid(2048 / BN, 1024 / BM, 4);  // (8, 8, 4) = 256 blocks
    // pass1: Et/Ot over q-parity; epilogue folds v' and splits p-parity
    gemm_eo<1><<<grid, 512, 0, stream>>>(Ce, Co, xe, xo, tTe, tTo, nullptr);
    // pass2: E2/O2 over p-parity; epilogue folds u', writes fp32 out
    gemm_eo<2><<<grid, 512, 0, stream>>>(Se, So, tTe, tTo, nullptr, nullptr, out);
}